// Round 1
// baseline (488.022 us; speedup 1.0000x reference)
//
#include <hip/hip_runtime.h>
#include <math.h>

#define BN 4096
#define DD 128
#define TILE 64
#define KC 64
#define LDSW 68   // 64 + 4 pad; 68%32==4 -> float4 reads land 2-way max (free)

// ws layout (floats): mag[BN] | nes[BN] | sum | cnt

__global__ void mag_kernel(const float* __restrict__ score, float* __restrict__ mag) {
    int row  = blockIdx.x * 4 + (threadIdx.x >> 6);
    int lane = threadIdx.x & 63;
    float2 v = *reinterpret_cast<const float2*>(score + row * DD + lane * 2);
    float s = v.x * v.x + v.y * v.y;
    #pragma unroll
    for (int off = 32; off > 0; off >>= 1) s += __shfl_xor(s, off);
    if (lane == 0) mag[row] = s;
}

__device__ __forceinline__ void gemm_tile(const float* __restrict__ score,
                                          int i0, int j0, int tid,
                                          float (&Asm)[TILE][LDSW], float (&Bsm)[TILE][LDSW],
                                          float (&acc)[4][4]) {
    const int g = tid >> 4;   // row group 0..15
    const int l = tid & 15;   // col group 0..15
    for (int kc = 0; kc < DD; kc += KC) {
        int r  = tid >> 4;
        int c4 = tid & 15;
        #pragma unroll
        for (int pass = 0; pass < 4; ++pass) {
            int rr = r + pass * 16;
            float4 va = *reinterpret_cast<const float4*>(score + (size_t)(i0 + rr) * DD + kc + c4 * 4);
            *reinterpret_cast<float4*>(&Asm[rr][c4 * 4]) = va;
            float4 vb = *reinterpret_cast<const float4*>(score + (size_t)(j0 + rr) * DD + kc + c4 * 4);
            *reinterpret_cast<float4*>(&Bsm[rr][c4 * 4]) = vb;
        }
        __syncthreads();
        #pragma unroll
        for (int k4 = 0; k4 < KC / 4; ++k4) {
            float4 a[4], b[4];
            #pragma unroll
            for (int p = 0; p < 4; ++p) a[p] = *reinterpret_cast<const float4*>(&Asm[g * 4 + p][k4 * 4]);
            #pragma unroll
            for (int q = 0; q < 4; ++q) b[q] = *reinterpret_cast<const float4*>(&Bsm[l * 4 + q][k4 * 4]);
            #pragma unroll
            for (int p = 0; p < 4; ++p)
                #pragma unroll
                for (int q = 0; q < 4; ++q)
                    acc[p][q] += a[p].x * b[q].x + a[p].y * b[q].y + a[p].z * b[q].z + a[p].w * b[q].w;
        }
        __syncthreads();
    }
}

__global__ __launch_bounds__(256)
void nes_kernel(const float* __restrict__ score, const int* __restrict__ target,
                const float* __restrict__ alphap, const float* __restrict__ mag,
                float* __restrict__ nes) {
    __shared__ float Asm[TILE][LDSW];
    __shared__ float Bsm[TILE][LDSW];
    const int i0 = blockIdx.x * TILE;
    const int j0 = blockIdx.y * TILE;
    const int tid = threadIdx.x;
    const int g = tid >> 4, l = tid & 15;
    const float alpha = alphap[0];

    float acc[4][4] = {};
    gemm_tile(score, i0, j0, tid, Asm, Bsm, acc);

    float e[4] = {0.f, 0.f, 0.f, 0.f};
    #pragma unroll
    for (int p = 0; p < 4; ++p) {
        int i = i0 + 4 * g + p;
        int ti = target[i];
        float mi = mag[i];
        #pragma unroll
        for (int q = 0; q < 4; ++q) {
            int j = j0 + 4 * l + q;
            float d2 = fmaxf(mi + mag[j] - 2.0f * acc[p][q], 0.0f);
            float dist = sqrtf(d2);
            if (ti != target[j]) e[p] += __expf(alpha - dist);
        }
    }
    // reduce across the 16 consecutive lanes sharing this row group
    #pragma unroll
    for (int p = 0; p < 4; ++p) {
        float v = e[p];
        v += __shfl_xor(v, 1);
        v += __shfl_xor(v, 2);
        v += __shfl_xor(v, 4);
        v += __shfl_xor(v, 8);
        if (l == 0) atomicAdd(&nes[i0 + 4 * g + p], v);
    }
}

__global__ __launch_bounds__(256)
void pos_kernel(const float* __restrict__ score, const int* __restrict__ target,
                const float* __restrict__ mag, const float* __restrict__ nes,
                float* __restrict__ sum, unsigned int* __restrict__ cnt) {
    if (blockIdx.y < blockIdx.x) return;   // only tiles that can hold j > i
    __shared__ float Asm[TILE][LDSW];
    __shared__ float Bsm[TILE][LDSW];
    const int i0 = blockIdx.x * TILE;
    const int j0 = blockIdx.y * TILE;
    const int tid = threadIdx.x;
    const int g = tid >> 4, l = tid & 15;

    float acc[4][4] = {};
    gemm_tile(score, i0, j0, tid, Asm, Bsm, acc);

    float s = 0.0f;
    unsigned int c = 0;
    #pragma unroll
    for (int p = 0; p < 4; ++p) {
        int i = i0 + 4 * g + p;
        int ti = target[i];
        float mi = mag[i];
        float ni = nes[i];
        #pragma unroll
        for (int q = 0; q < 4; ++q) {
            int j = j0 + 4 * l + q;
            if (j > i && ti == target[j]) {
                float d2 = fmaxf(mi + mag[j] - 2.0f * acc[p][q], 0.0f);
                float dist = sqrtf(d2);
                float t = __logf(ni + nes[j]) + dist;
                if (t > 0.0f) s += t * t;
                c++;
            }
        }
    }
    #pragma unroll
    for (int off = 1; off < 64; off <<= 1) {
        s += __shfl_xor(s, off);
        c += __shfl_xor(c, off);
    }
    if ((tid & 63) == 0) {
        atomicAdd(sum, s);
        atomicAdd(cnt, c);
    }
}

__global__ void finalize_kernel(const float* __restrict__ sum,
                                const unsigned int* __restrict__ cnt,
                                float* __restrict__ out) {
    out[0] = sum[0] / (2.0f * (float)cnt[0]);
}

extern "C" void kernel_launch(void* const* d_in, const int* in_sizes, int n_in,
                              void* d_out, int out_size, void* d_ws, size_t ws_size,
                              hipStream_t stream) {
    const float* score  = (const float*)d_in[0];
    const int*   target = (const int*)d_in[1];
    const float* alpha  = (const float*)d_in[2];
    float* out = (float*)d_out;

    float* mag = (float*)d_ws;
    float* nes = mag + BN;
    float* sum = nes + BN;
    unsigned int* cnt = (unsigned int*)(sum + 1);

    hipMemsetAsync(d_ws, 0, (2 * BN + 2) * sizeof(float), stream);

    mag_kernel<<<BN / 4, 256, 0, stream>>>(score, mag);

    dim3 grid(BN / TILE, BN / TILE);
    nes_kernel<<<grid, 256, 0, stream>>>(score, target, alpha, mag, nes);
    pos_kernel<<<grid, 256, 0, stream>>>(score, target, mag, nes, sum, cnt);
    finalize_kernel<<<1, 1, 0, stream>>>(sum, cnt, out);
}

// Round 2
// 198.766 us; speedup vs baseline: 2.4553x; 2.4553x over previous
//
#include <hip/hip_runtime.h>
#include <math.h>

#define BN 4096
#define DD 128
#define NCLS 64

typedef __attribute__((ext_vector_type(8))) short short8;
typedef __attribute__((ext_vector_type(4))) float f32x4;

__device__ __forceinline__ unsigned short f2bf(float f) {
    unsigned int u = __float_as_uint(f);
    u += 0x7FFFu + ((u >> 16) & 1u);   // RNE; inputs are finite normals
    return (unsigned short)(u >> 16);
}

__device__ __forceinline__ void gload_lds16(const void* g, void* l) {
    __builtin_amdgcn_global_load_lds(
        (const __attribute__((address_space(1))) unsigned int*)g,
        (__attribute__((address_space(3))) unsigned int*)l, 16, 0, 0);
}

// ws layout: sbf[BN*DD] bf16 | mag[BN] f32 | nes[BN] f32 | sum f32 | cnt u32 |
//            cls_cnt[64] | cls_start[64] | cls_list[BN]

__global__ __launch_bounds__(256)
void prep_kernel(const float* __restrict__ score, unsigned short* __restrict__ sbf,
                 float* __restrict__ mag) {
    int row  = blockIdx.x * 4 + (threadIdx.x >> 6);
    int lane = threadIdx.x & 63;
    float2 v = *reinterpret_cast<const float2*>(score + (size_t)row * DD + lane * 2);
    float s = v.x * v.x + v.y * v.y;
    #pragma unroll
    for (int off = 32; off; off >>= 1) s += __shfl_xor(s, off);
    ushort2 u; u.x = f2bf(v.x); u.y = f2bf(v.y);
    *reinterpret_cast<ushort2*>(sbf + (size_t)row * DD + lane * 2) = u;
    if (lane == 0) mag[row] = s;
}

__global__ __launch_bounds__(256)
void bucket_kernel(const int* __restrict__ target,
                   int* __restrict__ cls_cnt, int* __restrict__ cls_start,
                   int* __restrict__ cls_list) {
    __shared__ int hist[NCLS];
    __shared__ int offs[NCLS];
    int tid = threadIdx.x;
    if (tid < NCLS) hist[tid] = 0;
    __syncthreads();
    for (int i = tid; i < BN; i += 256) atomicAdd(&hist[target[i]], 1);
    __syncthreads();
    if (tid == 0) {
        int run = 0;
        for (int c = 0; c < NCLS; ++c) {
            cls_cnt[c] = hist[c];
            cls_start[c] = run;
            offs[c] = run;
            run += hist[c];
        }
    }
    __syncthreads();
    for (int i = tid; i < BN; i += 256) {
        int p = atomicAdd(&offs[target[i]], 1);
        cls_list[p] = i;
    }
}

// 128x128 tile, 4 waves (2x2), each wave 64x64 via 4x4 fragments of 16x16x32 bf16.
// LDS layout: linear row-major [128][128] bf16 per tile, but CONTENT is
// chunk-swizzled (16B chunk c of row r holds global chunk c^(r&7)) via
// pre-swizzled global_load_lds source; reads apply the same XOR.
__global__ __launch_bounds__(256)
void nes_kernel(const unsigned short* __restrict__ sbf, const int* __restrict__ target,
                const float* __restrict__ alphap, const float* __restrict__ mag,
                float* __restrict__ nes) {
    __shared__ __align__(16) unsigned short lds[2 * 128 * 128];   // A | B, 64 KB
    const int tid = threadIdx.x;
    const int w = tid >> 6, lane = tid & 63;
    const int lhi = lane >> 4, llo = lane & 15;
    const int i0 = blockIdx.x * 128, j0 = blockIdx.y * 128;

    // stage: each wave 32 rows per tile, 8 issues of 4 rows (64 lanes x 16B)
    #pragma unroll
    for (int t = 0; t < 8; ++t) {
        int rl = w * 32 + t * 4 + lhi;              // local row this lane feeds
        int ch = llo ^ (rl & 7);                    // pre-swizzled source chunk
        const unsigned short* srcA = sbf + (size_t)(i0 + rl) * DD + ch * 8;
        const unsigned short* srcB = sbf + (size_t)(j0 + rl) * DD + ch * 8;
        gload_lds16(srcA, lds + (w * 32 + t * 4) * 128);
        gload_lds16(srcB, lds + 128 * 128 + (w * 32 + t * 4) * 128);
    }
    __syncthreads();

    const int wr = w >> 1, wc = w & 1;
    f32x4 acc[4][4] = {};
    #pragma unroll
    for (int kk = 0; kk < 4; ++kk) {
        short8 a[4], b[4];
        #pragma unroll
        for (int m = 0; m < 4; ++m) {
            int r = wr * 64 + m * 16 + llo;
            int ch = (kk * 4 + lhi) ^ (r & 7);
            a[m] = *reinterpret_cast<const short8*>(lds + r * 128 + ch * 8);
        }
        #pragma unroll
        for (int n = 0; n < 4; ++n) {
            int r = wc * 64 + n * 16 + llo;
            int ch = (kk * 4 + lhi) ^ (r & 7);
            b[n] = *reinterpret_cast<const short8*>(lds + 128 * 128 + r * 128 + ch * 8);
        }
        #pragma unroll
        for (int m = 0; m < 4; ++m)
            #pragma unroll
            for (int n = 0; n < 4; ++n)
                acc[m][n] = __builtin_amdgcn_mfma_f32_16x16x32_bf16(a[m], b[n], acc[m][n], 0, 0, 0);
    }

    // epilogue: d2 -> dist -> masked exp -> per-row sums (C/D: col=lane&15, row=lhi*4+reg)
    const float alpha = alphap[0];
    float mj[4]; int tj[4];
    #pragma unroll
    for (int n = 0; n < 4; ++n) {
        int j = j0 + wc * 64 + n * 16 + llo;
        mj[n] = mag[j]; tj[n] = target[j];
    }
    #pragma unroll
    for (int m = 0; m < 4; ++m) {
        #pragma unroll
        for (int rg = 0; rg < 4; ++rg) {
            int i = i0 + wr * 64 + m * 16 + lhi * 4 + rg;
            float mi = mag[i];
            int ti = target[i];
            float rs = 0.f;
            #pragma unroll
            for (int n = 0; n < 4; ++n) {
                float d2 = fmaxf(mi + mj[n] - 2.0f * acc[m][n][rg], 0.0f);
                float dist = sqrtf(d2);
                rs += (ti != tj[n]) ? __expf(alpha - dist) : 0.0f;
            }
            rs += __shfl_xor(rs, 1);
            rs += __shfl_xor(rs, 2);
            rs += __shfl_xor(rs, 4);
            rs += __shfl_xor(rs, 8);
            if (llo == 0) atomicAdd(&nes[i], rs);
        }
    }
}

// one block per class; exact fp32 dots for the ~C(n_c,2) positive pairs
__global__ __launch_bounds__(256)
void pos_kernel(const float* __restrict__ score, const float* __restrict__ mag,
                const float* __restrict__ nes,
                const int* __restrict__ cls_cnt, const int* __restrict__ cls_start,
                const int* __restrict__ cls_list,
                float* __restrict__ sum, unsigned int* __restrict__ cntp) {
    const int c = blockIdx.x;
    const int n = cls_cnt[c], s0 = cls_start[c];
    const int tid = threadIdx.x;
    float s = 0.f;
    unsigned int cc = 0;
    for (int p = tid; p < n * n; p += 256) {
        int a = p / n, b = p - a * n;
        if (b <= a) continue;
        int i = cls_list[s0 + a], j = cls_list[s0 + b];
        const float4* ra = reinterpret_cast<const float4*>(score + (size_t)i * DD);
        const float4* rb = reinterpret_cast<const float4*>(score + (size_t)j * DD);
        float dot = 0.f;
        #pragma unroll 8
        for (int k = 0; k < DD / 4; ++k) {
            float4 x = ra[k], y = rb[k];
            dot += x.x * y.x + x.y * y.y + x.z * y.z + x.w * y.w;
        }
        float d2 = fmaxf(mag[i] + mag[j] - 2.0f * dot, 0.0f);
        float dist = sqrtf(d2);
        float t = __logf(nes[i] + nes[j]) + dist;
        if (t > 0.f) s += t * t;
        cc++;
    }
    #pragma unroll
    for (int off = 1; off < 64; off <<= 1) {
        s += __shfl_xor(s, off);
        cc += __shfl_xor(cc, off);
    }
    if ((tid & 63) == 0) { atomicAdd(sum, s); atomicAdd(cntp, cc); }
}

__global__ void finalize_kernel(const float* __restrict__ sum,
                                const unsigned int* __restrict__ cnt,
                                float* __restrict__ out) {
    out[0] = sum[0] / (2.0f * (float)cnt[0]);
}

extern "C" void kernel_launch(void* const* d_in, const int* in_sizes, int n_in,
                              void* d_out, int out_size, void* d_ws, size_t ws_size,
                              hipStream_t stream) {
    const float* score  = (const float*)d_in[0];
    const int*   target = (const int*)d_in[1];
    const float* alpha  = (const float*)d_in[2];
    float* out = (float*)d_out;

    unsigned short* sbf = (unsigned short*)d_ws;
    float* mag = (float*)((char*)d_ws + (size_t)BN * DD * 2);
    float* nes = mag + BN;
    float* sum = nes + BN;
    unsigned int* cnt = (unsigned int*)(sum + 1);
    int* cls_cnt   = (int*)(cnt + 1);
    int* cls_start = cls_cnt + NCLS;
    int* cls_list  = cls_start + NCLS;

    hipMemsetAsync(nes, 0, (BN + 2) * sizeof(float), stream);   // nes + sum + cnt

    prep_kernel<<<BN / 4, 256, 0, stream>>>(score, sbf, mag);
    bucket_kernel<<<1, 256, 0, stream>>>(target, cls_cnt, cls_start, cls_list);
    dim3 g(BN / 128, BN / 128);
    nes_kernel<<<g, 256, 0, stream>>>(sbf, target, alpha, mag, nes);
    pos_kernel<<<NCLS, 256, 0, stream>>>(score, mag, nes, cls_cnt, cls_start, cls_list, sum, cnt);
    finalize_kernel<<<1, 1, 0, stream>>>(sum, cnt, out);
}